// Round 5
// baseline (1492.991 us; speedup 1.0000x reference)
//
#include <hip/hip_runtime.h>

// ---------------- types & helpers ----------------
typedef __attribute__((ext_vector_type(8))) short bf16x8;
typedef __attribute__((ext_vector_type(4))) float f32x4;
typedef __attribute__((ext_vector_type(8))) unsigned short u16x8;

static __device__ __forceinline__ float b2f(unsigned short u) {
  unsigned v = ((unsigned)u) << 16;
  float f;
  __builtin_memcpy(&f, &v, 4);
  return f;
}
static __device__ __forceinline__ unsigned short f2b(float f) {
  unsigned u;
  __builtin_memcpy(&u, &f, 4);
  u = u + 0x7FFFu + ((u >> 16) & 1u);
  return (unsigned short)(u >> 16);
}
static __device__ __forceinline__ void load_lds16(const void* g, void* l) {
  __builtin_amdgcn_global_load_lds((const __attribute__((address_space(1))) unsigned int*)g,
                                   (__attribute__((address_space(3))) unsigned int*)l,
                                   16, 0, 0);
}

#define FENCE() asm volatile("" ::: "memory")
#define BARRIER() do { FENCE(); __builtin_amdgcn_s_barrier(); FENCE(); } while (0)

#define T_TOK 36864  // 4 * 64 * 144

// ---------------- fallback marker (ws too small) ----------------
__global__ void ws_marker_k(float* __restrict__ out, float wsmb) {
  int i = blockIdx.x * 256 + threadIdx.x;
  out[i] = (i == 0) ? wsmb : 0.f;
}

// ---------------- rope table (f64 precision, once per launch) ----------------
__global__ void rope_table_k(float* __restrict__ cosT, float* __restrict__ sinT) {
  int idx = blockIdx.x * 256 + threadIdx.x;  // < 9216*32, [pos][i]
  int i = idx & 31, p = idx >> 5;
  double invf = pow(10000.0, -(double)i / 32.0);
  double ang = (double)p * invf;
  cosT[idx] = (float)cos(ang);
  sinT[idx] = (float)sin(ang);
}

// ---------------- build merged sequence X (f32 / bf16 variants) ----------------
__global__ void build_xm_f32_k(const float* __restrict__ x, const float* __restrict__ rt,
                               float* __restrict__ X) {
  int i = blockIdx.x * 256 + threadIdx.x;  // float4 index, < T_TOK*128
  int c4 = i & 127;
  int t = i >> 7;
  int bl = t / 144;
  int j = t - bl * 144;
  int b = bl >> 6, l = bl & 63;
  float4 v;
  if (j < 128)
    v = ((const float4*)x)[((size_t)(b * 8192 + l * 128 + j)) * 128 + c4];
  else
    v = ((const float4*)rt)[(size_t)(j - 128) * 128 + c4];
  ((float4*)X)[i] = v;
}

__global__ void build_xm_bf16_k(const float* __restrict__ x, const float* __restrict__ rt,
                                unsigned short* __restrict__ X) {
  int i = blockIdx.x * 256 + threadIdx.x;  // u16x8 chunk index, < T_TOK*64
  int c8 = i & 63;
  int t = i >> 6;
  int bl = t / 144;
  int j = t - bl * 144;
  int b = bl >> 6, l = bl & 63;
  const float4* src;
  if (j < 128)
    src = (const float4*)x + ((size_t)(b * 8192 + l * 128 + j)) * 128 + c8 * 2;
  else
    src = (const float4*)rt + (size_t)(j - 128) * 128 + c8 * 2;
  float4 a = src[0], bq = src[1];
  u16x8 o;
  o[0] = f2b(a.x); o[1] = f2b(a.y); o[2] = f2b(a.z); o[3] = f2b(a.w);
  o[4] = f2b(bq.x); o[5] = f2b(bq.y); o[6] = f2b(bq.z); o[7] = f2b(bq.w);
  *(u16x8*)(X + (size_t)i * 8) = o;
}

// ---------------- gather router-token outputs ----------------
__global__ void gather_out_f32_k(const float* __restrict__ X, float* __restrict__ out) {
  int i = blockIdx.x * 256 + threadIdx.x;  // float4 idx, < 524288
  int c4 = i & 127;
  int r = (i >> 7) & 15;
  int l = (i >> 11) & 63;
  int b = i >> 17;
  size_t t = ((size_t)(b * 64 + l)) * 144 + 128 + r;
  ((float4*)out)[i] = ((const float4*)X)[t * 128 + c4];
}

__global__ void gather_out_bf16_k(const unsigned short* __restrict__ X, float* __restrict__ out) {
  int i = blockIdx.x * 256 + threadIdx.x;  // u16x8 chunk idx, < 262144
  int c8 = i & 63;
  int r = (i >> 6) & 15;
  int l = (i >> 10) & 63;
  int b = i >> 16;
  size_t t = ((size_t)(b * 64 + l)) * 144 + 128 + r;
  u16x8 v = *(const u16x8*)(X + t * 512 + c8 * 8);
  float4 o0 = {b2f(v[0]), b2f(v[1]), b2f(v[2]), b2f(v[3])};
  float4 o1 = {b2f(v[4]), b2f(v[5]), b2f(v[6]), b2f(v[7])};
  size_t oi = (size_t)i * 8;
  *(float4*)(out + oi) = o0;
  *(float4*)(out + oi + 4) = o1;
}

// ---------------- RMSNorm X -> bf16 (one wave per row) ----------------
template <int XBF>
__global__ __launch_bounds__(256) void rmsnorm_k(const void* __restrict__ Xv,
                                                 const float* __restrict__ w,
                                                 unsigned short* __restrict__ XN) {
  int lane = threadIdx.x & 63, wv = threadIdx.x >> 6;
  size_t row = (size_t)blockIdx.x * 4 + wv;
  float v[8];
  if (XBF) {
    u16x8 a = *(const u16x8*)((const unsigned short*)Xv + row * 512 + lane * 8);
#pragma unroll
    for (int e = 0; e < 8; ++e) v[e] = b2f(a[e]);
  } else {
    const float4* xr = (const float4*)((const float*)Xv + row * 512);
    float4 a = xr[lane * 2], b = xr[lane * 2 + 1];
    v[0] = a.x; v[1] = a.y; v[2] = a.z; v[3] = a.w;
    v[4] = b.x; v[5] = b.y; v[6] = b.z; v[7] = b.w;
  }
  float ss = 0.f;
#pragma unroll
  for (int e = 0; e < 8; ++e) ss += v[e] * v[e];
#pragma unroll
  for (int off = 32; off; off >>= 1) ss += __shfl_xor(ss, off);
  float inv = rsqrtf(ss * (1.0f / 512.0f) + 1e-5f);
  const float4* w4 = (const float4*)w;
  float4 w0 = w4[lane * 2], w1 = w4[lane * 2 + 1];
  float wf[8] = {w0.x, w0.y, w0.z, w0.w, w1.x, w1.y, w1.z, w1.w};
  u16x8 o;
#pragma unroll
  for (int e = 0; e < 8; ++e) o[e] = f2b(v[e] * inv * wf[e]);
  *(u16x8*)(XN + row * 512 + lane * 8) = o;
}

// ---------------- weight transpose-convert f32[K][N] -> bf16[N][K] ----------------
__global__ void wconv_k(const float* __restrict__ in, unsigned short* __restrict__ out,
                        int K, int N, int upmap) {
  __shared__ float t[32][33];
  int tx = threadIdx.x & 31, ty = threadIdx.x >> 5;  // ty 0..7
  int n0 = blockIdx.x * 32, k0 = blockIdx.y * 32;
  int half = N >> 1;
#pragma unroll
  for (int i = 0; i < 32; i += 8) {
    int n = n0 + tx;
    int nsrc = upmap ? (((n >> 5) << 4) + (n & 15) + (((n >> 4) & 1) ? half : 0)) : n;
    t[ty + i][tx] = in[(size_t)(k0 + ty + i) * N + nsrc];
  }
  __syncthreads();
#pragma unroll
  for (int i = 0; i < 32; i += 8)
    out[(size_t)(n0 + ty + i) * K + k0 + tx] = f2b(t[tx][ty + i]);
}

// ---------------- pipelined MFMA GEMM (T3+T4+T5): BM=256, BN=128, BK=64 ----------------
// 8 waves (4Mx2N), 3 LDS buffers (48 KiB each), counted vmcnt, setprio MFMA clusters.
// C[M][ldc] = A[M][K](bf16) * BT[N][K](bf16)^T.
// EPI 0: store bf16. EPI 1: f32 residual add. EPI 2: fused SwiGLU. EPI 3: bf16 residual.
template <int EPI>
__global__ __launch_bounds__(512, 2) void gemm8_k(const unsigned short* __restrict__ A,
                                                  const unsigned short* __restrict__ BT,
                                                  void* __restrict__ Cv, int K, int ldc) {
  __shared__ short lds[73728];  // 3 * (256*64 + 128*64) shorts = 144 KiB
  const int tid = threadIdx.x;
  const int lane = tid & 63, wv = tid >> 6;
  const int wr = wv >> 1, wc = wv & 1;  // wr 0..3 (M), wc 0..1 (N)
  const int lr = lane & 15, kg = lane >> 4;
  const int m0 = blockIdx.x * 256, n0 = blockIdx.y * 128;
  const int NT = K >> 6;

  f32x4 acc[4][4];
#pragma unroll
  for (int m = 0; m < 4; ++m)
#pragma unroll
    for (int n = 0; n < 4; ++n) acc[m][n] = (f32x4){0.f, 0.f, 0.f, 0.f};

  // --- staging: 6 x 16B-chunk loads per thread per K-tile (j 0..3 = A, 4..5 = B).
  // LDS dest is wave-uniform; per-lane source pre-inverse-swizzled (slot ^ row&7).
  auto STAGE_A = [&](int bi, int kt, int j) {
    int cu = j * 512 + wv * 64;            // uniform 16B-chunk base
    int Ob = (cu + lane) << 4;             // per-lane byte offset (A region, < 32768)
    int row = Ob >> 7;
    int ss = ((Ob >> 4) & 7) ^ (row & 7);
    load_lds16(A + (size_t)(m0 + row) * K + kt + ss * 8,
               (char*)lds + bi * 49152 + (cu << 4));
  };
  auto STAGE_B = [&](int bi, int kt, int j) {
    int cu = j * 512 + wv * 64;
    int o2 = ((cu + lane) << 4) - 32768;   // B region offset
    int row = o2 >> 7;
    int ss = ((o2 >> 4) & 7) ^ (row & 7);
    load_lds16(BT + (size_t)(n0 + row) * K + kt + ss * 8,
               (char*)lds + bi * 49152 + (cu << 4));
  };
  auto LDA = [&](int bi, int mf, int kk) -> bf16x8 {
    int row = wr * 64 + mf * 16 + lr;      // 0..255
    int off = bi * 49152 + row * 128 + (((kk * 4 + kg) ^ (row & 7)) << 4);
    return *(const bf16x8*)((const char*)lds + off);
  };
  auto LDB = [&](int bi, int nf, int kk) -> bf16x8 {
    int row = wc * 64 + nf * 16 + lr;      // 0..127
    int off = bi * 49152 + 32768 + row * 128 + (((kk * 4 + kg) ^ (row & 7)) << 4);
    return *(const bf16x8*)((const char*)lds + off);
  };

  // --- prologue: stage tiles 0 and 1; wait tile 0 (leave tile 1 in flight).
#pragma unroll
  for (int j = 0; j < 4; ++j) STAGE_A(0, 0, j);
  STAGE_B(0, 0, 4); STAGE_B(0, 0, 5);
#pragma unroll
  for (int j = 0; j < 4; ++j) STAGE_A(1, 64, j);
  STAGE_B(1, 64, 4); STAGE_B(1, 64, 5);
  asm volatile("s_waitcnt vmcnt(6)" ::: "memory");
  BARRIER();

  int bi = 0;
  for (int t = 0; t < NT; ++t) {
    const int kt2 = (t + 2) << 6;
    int b2 = bi + 2; if (b2 >= 3) b2 -= 3;
    const bool st = (t + 2) < NT;

    // ---- phase 1 (kk=0): 8 ds_read_b128 || 3 stage loads -> bar -> 16 MFMA -> bar
    {
      bf16x8 af[4], bg[4];
#pragma unroll
      for (int mf = 0; mf < 4; ++mf) af[mf] = LDA(bi, mf, 0);
#pragma unroll
      for (int nf = 0; nf < 4; ++nf) bg[nf] = LDB(bi, nf, 0);
      if (st) { STAGE_A(b2, kt2, 0); STAGE_A(b2, kt2, 1); STAGE_A(b2, kt2, 2); }
      BARRIER();
      __builtin_amdgcn_s_setprio(1);
#pragma unroll
      for (int mf = 0; mf < 4; ++mf)
#pragma unroll
        for (int nf = 0; nf < 4; ++nf)
          acc[mf][nf] = __builtin_amdgcn_mfma_f32_16x16x32_bf16(af[mf], bg[nf], acc[mf][nf], 0, 0, 0);
      __builtin_amdgcn_s_setprio(0);
      BARRIER();
    }
    // ---- phase 2 (kk=1): 8 ds_read_b128 || 3 stage loads -> bar -> 16 MFMA -> vmcnt -> bar
    {
      bf16x8 af[4], bg[4];
#pragma unroll
      for (int mf = 0; mf < 4; ++mf) af[mf] = LDA(bi, mf, 1);
#pragma unroll
      for (int nf = 0; nf < 4; ++nf) bg[nf] = LDB(bi, nf, 1);
      if (st) { STAGE_A(b2, kt2, 3); STAGE_B(b2, kt2, 4); STAGE_B(b2, kt2, 5); }
      BARRIER();
      __builtin_amdgcn_s_setprio(1);
#pragma unroll
      for (int mf = 0; mf < 4; ++mf)
#pragma unroll
        for (int nf = 0; nf < 4; ++nf)
          acc[mf][nf] = __builtin_amdgcn_mfma_f32_16x16x32_bf16(af[mf], bg[nf], acc[mf][nf], 0, 0, 0);
      __builtin_amdgcn_s_setprio(0);
      if (t + 1 < NT) {
        if (st) asm volatile("s_waitcnt vmcnt(6)" ::: "memory");  // tile t+1 landed; t+2 in flight
        else    asm volatile("s_waitcnt vmcnt(0)" ::: "memory");  // pipeline tail
      }
      BARRIER();
    }
    ++bi; if (bi == 3) bi = 0;
  }

  // ---- epilogue
  if (EPI == 0) {
    unsigned short* Cb = (unsigned short*)Cv;
#pragma unroll
    for (int m = 0; m < 4; ++m)
#pragma unroll
      for (int n = 0; n < 4; ++n)
#pragma unroll
        for (int r = 0; r < 4; ++r) {
          int row = m0 + wr * 64 + m * 16 + kg * 4 + r;
          int col = n0 + wc * 64 + n * 16 + lr;
          Cb[(size_t)row * ldc + col] = f2b(acc[m][n][r]);
        }
  } else if (EPI == 1) {
    float* Cf = (float*)Cv;
#pragma unroll
    for (int m = 0; m < 4; ++m)
#pragma unroll
      for (int n = 0; n < 4; ++n)
#pragma unroll
        for (int r = 0; r < 4; ++r) {
          size_t idx = (size_t)(m0 + wr * 64 + m * 16 + kg * 4 + r) * ldc +
                       (n0 + wc * 64 + n * 16 + lr);
          Cf[idx] += acc[m][n][r];
        }
  } else if (EPI == 3) {
    unsigned short* Cb = (unsigned short*)Cv;
#pragma unroll
    for (int m = 0; m < 4; ++m)
#pragma unroll
      for (int n = 0; n < 4; ++n)
#pragma unroll
        for (int r = 0; r < 4; ++r) {
          size_t idx = (size_t)(m0 + wr * 64 + m * 16 + kg * 4 + r) * ldc +
                       (n0 + wc * 64 + n * 16 + lr);
          Cb[idx] = f2b(b2f(Cb[idx]) + acc[m][n][r]);
        }
  } else {
    unsigned short* Hb = (unsigned short*)Cv;
#pragma unroll
    for (int m = 0; m < 4; ++m)
#pragma unroll
      for (int p = 0; p < 2; ++p) {
        int n = p * 2;
        int colb = ((n0 + wc * 64 + n * 16) >> 1) + lr;
#pragma unroll
        for (int r = 0; r < 4; ++r) {
          float a = acc[m][n][r], bb = acc[m][n + 1][r];
          float hv = a / (1.f + __expf(-a)) * bb;  // silu(u1)*u2
          int row = m0 + wr * 64 + m * 16 + kg * 4 + r;
          Hb[(size_t)row * ldc + colb] = f2b(hv);
        }
      }
  }
}

// ---------------- fused block attention (one block = one (b,l,h)) ----------------
__global__ __launch_bounds__(256) void attn_k(const unsigned short* __restrict__ QKV,
                                              unsigned short* __restrict__ O,
                                              const float* __restrict__ cosT,
                                              const float* __restrict__ sinT,
                                              int blk0) {
  __shared__ short Ks[144 * 72];     // rotated+scaled K, pad 72 for banks
  __shared__ short Vt[64 * 168];     // V transposed [dim][token], pad 168
  __shared__ short Ps[4][16 * 168];  // per-wave P tile
  int tid = threadIdx.x, lane = tid & 63, wv = tid >> 6;
  int lr = lane & 15, kg = lane >> 4;
  int blk = blockIdx.x, h = blk & 7, bl = blk >> 3;
  size_t t0 = (size_t)bl * 144;
  int posB = ((blk0 + bl) & 63) * 144;

  for (int idx = tid; idx < 144 * 4; idx += 256) {
    int j = idx >> 2, dg = idx & 3;
    const unsigned short* kr = QKV + (t0 + j) * 1536 + 512 + h * 64;
    u16x8 k1 = *(const u16x8*)(kr + dg * 8);
    u16x8 k2 = *(const u16x8*)(kr + 32 + dg * 8);
    const float* cp = cosT + (size_t)(posB + j) * 32 + dg * 8;
    const float* sp = sinT + (size_t)(posB + j) * 32 + dg * 8;
    u16x8 r1, r2;
#pragma unroll
    for (int e = 0; e < 8; ++e) {
      float c = cp[e], s = sp[e];
      float x1 = b2f(k1[e]) * 0.125f, x2 = b2f(k2[e]) * 0.125f;
      r1[e] = f2b(x1 * c + x2 * s);
      r2[e] = f2b(x2 * c - x1 * s);
    }
    *(u16x8*)(Ks + j * 72 + dg * 8) = r1;
    *(u16x8*)(Ks + j * 72 + 32 + dg * 8) = r2;
  }
  for (int idx = tid; idx < 144 * 8; idx += 256) {
    int j = idx >> 3, dg = idx & 7;
    u16x8 v = *(const u16x8*)(QKV + (t0 + j) * 1536 + 1024 + h * 64 + dg * 8);
#pragma unroll
    for (int e = 0; e < 8; ++e) Vt[(dg * 8 + e) * 168 + j] = v[e];
  }
  for (int idx = tid; idx < 64 * 16; idx += 256)
    Vt[(idx >> 4) * 168 + 144 + (idx & 15)] = 0;
  __syncthreads();

  for (int rt = wv; rt < 9; rt += 4) {
    int row = rt * 16 + lr;
    int pos = posB + row;
    const unsigned short* qr = QKV + (t0 + row) * 1536 + h * 64;
    u16x8 q1 = *(const u16x8*)(qr + kg * 8);
    u16x8 q2 = *(const u16x8*)(qr + 32 + kg * 8);
    const float* cp = cosT + (size_t)pos * 32 + kg * 8;
    const float* sp = sinT + (size_t)pos * 32 + kg * 8;
    bf16x8 aq0, aq1;
#pragma unroll
    for (int e = 0; e < 8; ++e) {
      float c = cp[e], s = sp[e];
      float x1 = b2f(q1[e]), x2 = b2f(q2[e]);
      aq0[e] = (short)f2b(x1 * c + x2 * s);
      aq1[e] = (short)f2b(x2 * c - x1 * s);
    }
    f32x4 acc[9];
#pragma unroll
    for (int ct = 0; ct < 9; ++ct) acc[ct] = (f32x4){0.f, 0.f, 0.f, 0.f};
#pragma unroll
    for (int ct = 0; ct < 9; ++ct) {
      const short* kb = Ks + (ct * 16 + lr) * 72 + kg * 8;
      bf16x8 b0 = *(const bf16x8*)kb;
      bf16x8 b1 = *(const bf16x8*)(kb + 32);
      acc[ct] = __builtin_amdgcn_mfma_f32_16x16x32_bf16(aq0, b0, acc[ct], 0, 0, 0);
      acc[ct] = __builtin_amdgcn_mfma_f32_16x16x32_bf16(aq1, b1, acc[ct], 0, 0, 0);
    }
    float invs[4];
#pragma unroll
    for (int r = 0; r < 4; ++r) {
      float m = acc[0][r];
#pragma unroll
      for (int ct = 1; ct < 9; ++ct) m = fmaxf(m, acc[ct][r]);
#pragma unroll
      for (int off = 1; off < 16; off <<= 1) m = fmaxf(m, __shfl_xor(m, off));
      float sum = 0.f;
#pragma unroll
      for (int ct = 0; ct < 9; ++ct) {
        float e = __expf(acc[ct][r] - m);
        acc[ct][r] = e;
        sum += e;
      }
#pragma unroll
      for (int off = 1; off < 16; off <<= 1) sum += __shfl_xor(sum, off);
      invs[r] = 1.f / sum;
    }
    short* P = &Ps[wv][0];
#pragma unroll
    for (int ct = 0; ct < 9; ++ct)
#pragma unroll
      for (int r = 0; r < 4; ++r)
        P[(kg * 4 + r) * 168 + ct * 16 + lr] = (short)f2b(acc[ct][r] * invs[r]);
#pragma unroll
    for (int z = 0; z < 4; ++z) {
      int e = lane * 4 + z;
      P[(e >> 4) * 168 + 144 + (e & 15)] = 0;
    }
    f32x4 oacc[4];
#pragma unroll
    for (int n = 0; n < 4; ++n) oacc[n] = (f32x4){0.f, 0.f, 0.f, 0.f};
#pragma unroll
    for (int kc = 0; kc < 5; ++kc) {
      bf16x8 pa = *(const bf16x8*)(P + lr * 168 + kc * 32 + kg * 8);
#pragma unroll
      for (int n = 0; n < 4; ++n) {
        bf16x8 vb = *(const bf16x8*)(Vt + (n * 16 + lr) * 168 + kc * 32 + kg * 8);
        oacc[n] = __builtin_amdgcn_mfma_f32_16x16x32_bf16(pa, vb, oacc[n], 0, 0, 0);
      }
    }
#pragma unroll
    for (int n = 0; n < 4; ++n)
#pragma unroll
      for (int r = 0; r < 4; ++r) {
        int orow = rt * 16 + kg * 4 + r;
        O[(t0 + orow) * 512 + h * 64 + n * 16 + lr] = f2b(oacc[n][r]);
      }
  }
}

// ---------------- launcher ----------------
extern "C" void kernel_launch(void* const* d_in, const int* in_sizes, int n_in,
                              void* d_out, int out_size, void* d_ws, size_t ws_size,
                              hipStream_t stream) {
  (void)in_sizes; (void)n_in; (void)out_size;
  const float* x = (const float*)d_in[0];
  const float* rtok = (const float*)d_in[1];
  const float* aw[2] = {(const float*)d_in[2], (const float*)d_in[8]};
  const float* ow[2] = {(const float*)d_in[3], (const float*)d_in[9]};
  const float* uw[2] = {(const float*)d_in[4], (const float*)d_in[10]};
  const float* dw[2] = {(const float*)d_in[5], (const float*)d_in[11]};
  const float* an[2] = {(const float*)d_in[6], (const float*)d_in[12]};
  const float* fn[2] = {(const float*)d_in[7], (const float*)d_in[13]};

  // weights (16,777,216 B) + rope tables (2,359,296 B) are always resident.
  const size_t wfix = 16777216ull + 2359296ull;
  // tiers: {X dtype, chunks}. need = wfix + Xbytes + CT*5120 (XN + S1, bf16).
  // CT = T_TOK/chunks must be divisible by 256 (gemm8 BM) -> chunks <= 16.
  const int tier_xb[5] = {0, 0, 0, 1, 1};
  const int tier_ch[5] = {2, 4, 8, 8, 16};
  int ti = -1;
  for (int i = 0; i < 5; ++i) {
    size_t xbytes = (size_t)T_TOK * (tier_xb[i] ? 1024 : 2048);
    size_t need = wfix + xbytes + ((size_t)T_TOK / tier_ch[i]) * 5120;
    if (ws_size >= need) { ti = i; break; }
  }
  if (ti < 0) {
    ws_marker_k<<<8192, 256, 0, stream>>>((float*)d_out, (float)(ws_size >> 20));
    return;
  }
  const int xbf = tier_xb[ti];
  const int chunks = tier_ch[ti];
  const int CT = T_TOK / chunks;  // multiple of 2304 -> divisible by 256 and 144
  const int MT = CT / 256, AB = CT / 144;

  char* ws = (char*)d_ws;
  size_t woff = 0;
  unsigned short *WqkvT[2], *WoT[2], *WupT[2], *WdnT[2];
  for (int l = 0; l < 2; ++l) {
    WqkvT[l] = (unsigned short*)(ws + woff); woff += 1536ull * 512 * 2;
    WoT[l]   = (unsigned short*)(ws + woff); woff += 512ull * 512 * 2;
    WupT[l]  = (unsigned short*)(ws + woff); woff += 4096ull * 512 * 2;
    WdnT[l]  = (unsigned short*)(ws + woff); woff += 512ull * 2048 * 2;
  }
  float* cosT = (float*)(ws + woff); woff += 9216ull * 32 * 4;
  float* sinT = (float*)(ws + woff); woff += 9216ull * 32 * 4;
  char* Xraw = ws + woff; woff += (size_t)T_TOK * (xbf ? 1024 : 2048);
  unsigned short* XN = (unsigned short*)(ws + woff);               // CT*512 bf16 (also O)
  unsigned short* S1 = (unsigned short*)(ws + woff + (size_t)CT * 1024);  // QKV / H

  rope_table_k<<<1152, 256, 0, stream>>>(cosT, sinT);
  if (xbf)
    build_xm_bf16_k<<<9216, 256, 0, stream>>>(x, rtok, (unsigned short*)Xraw);
  else
    build_xm_f32_k<<<18432, 256, 0, stream>>>(x, rtok, (float*)Xraw);
  for (int l = 0; l < 2; ++l) {
    wconv_k<<<dim3(48, 16), 256, 0, stream>>>(aw[l], WqkvT[l], 512, 1536, 0);
    wconv_k<<<dim3(16, 16), 256, 0, stream>>>(ow[l], WoT[l], 512, 512, 0);
    wconv_k<<<dim3(128, 16), 256, 0, stream>>>(uw[l], WupT[l], 512, 4096, 1);
    wconv_k<<<dim3(16, 64), 256, 0, stream>>>(dw[l], WdnT[l], 2048, 512, 0);
  }
  for (int l = 0; l < 2; ++l) {
    for (int c = 0; c < chunks; ++c) {
      char* Xc = Xraw + (size_t)c * CT * (xbf ? 1024 : 2048);
      if (xbf) {
        rmsnorm_k<1><<<CT / 4, 256, 0, stream>>>(Xc, an[l], XN);
        gemm8_k<0><<<dim3(MT, 12), 512, 0, stream>>>(XN, WqkvT[l], (void*)S1, 512, 1536);
        attn_k<<<AB * 8, 256, 0, stream>>>(S1, XN, cosT, sinT, c * AB);
        gemm8_k<3><<<dim3(MT, 4), 512, 0, stream>>>(XN, WoT[l], (void*)Xc, 512, 512);
        rmsnorm_k<1><<<CT / 4, 256, 0, stream>>>(Xc, fn[l], XN);
        gemm8_k<2><<<dim3(MT, 32), 512, 0, stream>>>(XN, WupT[l], (void*)S1, 512, 2048);
        gemm8_k<3><<<dim3(MT, 4), 512, 0, stream>>>(S1, WdnT[l], (void*)Xc, 2048, 512);
      } else {
        rmsnorm_k<0><<<CT / 4, 256, 0, stream>>>(Xc, an[l], XN);
        gemm8_k<0><<<dim3(MT, 12), 512, 0, stream>>>(XN, WqkvT[l], (void*)S1, 512, 1536);
        attn_k<<<AB * 8, 256, 0, stream>>>(S1, XN, cosT, sinT, c * AB);
        gemm8_k<1><<<dim3(MT, 4), 512, 0, stream>>>(XN, WoT[l], (void*)Xc, 512, 512);
        rmsnorm_k<0><<<CT / 4, 256, 0, stream>>>(Xc, fn[l], XN);
        gemm8_k<2><<<dim3(MT, 32), 512, 0, stream>>>(XN, WupT[l], (void*)S1, 512, 2048);
        gemm8_k<1><<<dim3(MT, 4), 512, 0, stream>>>(S1, WdnT[l], (void*)Xc, 2048, 512);
      }
    }
  }
  if (xbf)
    gather_out_bf16_k<<<1024, 256, 0, stream>>>((const unsigned short*)Xraw, (float*)d_out);
  else
    gather_out_f32_k<<<2048, 256, 0, stream>>>((const float*)Xraw, (float*)d_out);
}

// Round 6
// 1065.611 us; speedup vs baseline: 1.4011x; 1.4011x over previous
//
#include <hip/hip_runtime.h>

// ---------------- types & helpers ----------------
typedef __attribute__((ext_vector_type(8))) short bf16x8;
typedef __attribute__((ext_vector_type(4))) float f32x4;
typedef __attribute__((ext_vector_type(8))) unsigned short u16x8;

static __device__ __forceinline__ float b2f(unsigned short u) {
  unsigned v = ((unsigned)u) << 16;
  float f;
  __builtin_memcpy(&f, &v, 4);
  return f;
}
static __device__ __forceinline__ unsigned short f2b(float f) {
  unsigned u;
  __builtin_memcpy(&u, &f, 4);
  u = u + 0x7FFFu + ((u >> 16) & 1u);
  return (unsigned short)(u >> 16);
}
static __device__ __forceinline__ void load_lds16(const void* g, void* l) {
  __builtin_amdgcn_global_load_lds((const __attribute__((address_space(1))) unsigned int*)g,
                                   (__attribute__((address_space(3))) unsigned int*)l,
                                   16, 0, 0);
}

#define T_TOK 36864  // 4 * 64 * 144

// ---------------- fallback marker (ws too small) ----------------
__global__ void ws_marker_k(float* __restrict__ out, float wsmb) {
  int i = blockIdx.x * 256 + threadIdx.x;
  out[i] = (i == 0) ? wsmb : 0.f;
}

// ---------------- rope table (f64 precision, once per launch) ----------------
__global__ void rope_table_k(float* __restrict__ cosT, float* __restrict__ sinT) {
  int idx = blockIdx.x * 256 + threadIdx.x;  // < 9216*32, [pos][i]
  int i = idx & 31, p = idx >> 5;
  double invf = pow(10000.0, -(double)i / 32.0);
  double ang = (double)p * invf;
  cosT[idx] = (float)cos(ang);
  sinT[idx] = (float)sin(ang);
}

// ---------------- build merged sequence X (f32 / bf16 variants) ----------------
__global__ void build_xm_f32_k(const float* __restrict__ x, const float* __restrict__ rt,
                               float* __restrict__ X) {
  int i = blockIdx.x * 256 + threadIdx.x;  // float4 index, < T_TOK*128
  int c4 = i & 127;
  int t = i >> 7;
  int bl = t / 144;
  int j = t - bl * 144;
  int b = bl >> 6, l = bl & 63;
  float4 v;
  if (j < 128)
    v = ((const float4*)x)[((size_t)(b * 8192 + l * 128 + j)) * 128 + c4];
  else
    v = ((const float4*)rt)[(size_t)(j - 128) * 128 + c4];
  ((float4*)X)[i] = v;
}

__global__ void build_xm_bf16_k(const float* __restrict__ x, const float* __restrict__ rt,
                                unsigned short* __restrict__ X) {
  int i = blockIdx.x * 256 + threadIdx.x;  // u16x8 chunk index, < T_TOK*64
  int c8 = i & 63;
  int t = i >> 6;
  int bl = t / 144;
  int j = t - bl * 144;
  int b = bl >> 6, l = bl & 63;
  const float4* src;
  if (j < 128)
    src = (const float4*)x + ((size_t)(b * 8192 + l * 128 + j)) * 128 + c8 * 2;
  else
    src = (const float4*)rt + (size_t)(j - 128) * 128 + c8 * 2;
  float4 a = src[0], bq = src[1];
  u16x8 o;
  o[0] = f2b(a.x); o[1] = f2b(a.y); o[2] = f2b(a.z); o[3] = f2b(a.w);
  o[4] = f2b(bq.x); o[5] = f2b(bq.y); o[6] = f2b(bq.z); o[7] = f2b(bq.w);
  *(u16x8*)(X + (size_t)i * 8) = o;
}

// ---------------- gather router rows of XN (bf16) -> compact RXN ----------------
__global__ void gather_rxn_k(const unsigned short* __restrict__ XN,
                             unsigned short* __restrict__ RXN) {
  int i = blockIdx.x * 256 + threadIdx.x;  // u16x8 chunks, < RT*64
  int c8 = i & 63, rt = i >> 6;
  int t = (rt >> 4) * 144 + 128 + (rt & 15);
  *(u16x8*)(RXN + (size_t)rt * 512 + c8 * 8) =
      *(const u16x8*)(XN + (size_t)t * 512 + c8 * 8);
}

// ---------------- gather router rows of X -> d_out (f32 residual base) ----------------
template <int XBF>
__global__ void gather_rx_k(const void* __restrict__ Xv, float* __restrict__ outc) {
  int i = blockIdx.x * 256 + threadIdx.x;  // 8-elem chunks, < RT*64
  int c8 = i & 63, rt = i >> 6;
  int t = (rt >> 4) * 144 + 128 + (rt & 15);
  float4 o0, o1;
  if (XBF) {
    u16x8 v = *(const u16x8*)((const unsigned short*)Xv + (size_t)t * 512 + c8 * 8);
    o0 = (float4){b2f(v[0]), b2f(v[1]), b2f(v[2]), b2f(v[3])};
    o1 = (float4){b2f(v[4]), b2f(v[5]), b2f(v[6]), b2f(v[7])};
  } else {
    const float4* p = (const float4*)Xv + (size_t)t * 128 + c8 * 2;
    o0 = p[0]; o1 = p[1];
  }
  float* dst = outc + (size_t)rt * 512 + c8 * 8;
  *(float4*)dst = o0;
  *(float4*)(dst + 4) = o1;
}

// ---------------- RMSNorm X -> bf16 (one wave per row) ----------------
template <int XBF>
__global__ __launch_bounds__(256) void rmsnorm_k(const void* __restrict__ Xv,
                                                 const float* __restrict__ w,
                                                 unsigned short* __restrict__ XN) {
  int lane = threadIdx.x & 63, wv = threadIdx.x >> 6;
  size_t row = (size_t)blockIdx.x * 4 + wv;
  float v[8];
  if (XBF) {
    u16x8 a = *(const u16x8*)((const unsigned short*)Xv + row * 512 + lane * 8);
#pragma unroll
    for (int e = 0; e < 8; ++e) v[e] = b2f(a[e]);
  } else {
    const float4* xr = (const float4*)((const float*)Xv + row * 512);
    float4 a = xr[lane * 2], b = xr[lane * 2 + 1];
    v[0] = a.x; v[1] = a.y; v[2] = a.z; v[3] = a.w;
    v[4] = b.x; v[5] = b.y; v[6] = b.z; v[7] = b.w;
  }
  float ss = 0.f;
#pragma unroll
  for (int e = 0; e < 8; ++e) ss += v[e] * v[e];
#pragma unroll
  for (int off = 32; off; off >>= 1) ss += __shfl_xor(ss, off);
  float inv = rsqrtf(ss * (1.0f / 512.0f) + 1e-5f);
  const float4* w4 = (const float4*)w;
  float4 w0 = w4[lane * 2], w1 = w4[lane * 2 + 1];
  float wf[8] = {w0.x, w0.y, w0.z, w0.w, w1.x, w1.y, w1.z, w1.w};
  u16x8 o;
#pragma unroll
  for (int e = 0; e < 8; ++e) o[e] = f2b(v[e] * inv * wf[e]);
  *(u16x8*)(XN + row * 512 + lane * 8) = o;
}

// ---------------- weight transpose-convert f32[K][N] -> bf16[N][K] ----------------
__global__ void wconv_k(const float* __restrict__ in, unsigned short* __restrict__ out,
                        int K, int N, int upmap) {
  __shared__ float t[32][33];
  int tx = threadIdx.x & 31, ty = threadIdx.x >> 5;  // ty 0..7
  int n0 = blockIdx.x * 32, k0 = blockIdx.y * 32;
  int half = N >> 1;
#pragma unroll
  for (int i = 0; i < 32; i += 8) {
    int n = n0 + tx;
    int nsrc = upmap ? (((n >> 5) << 4) + (n & 15) + (((n >> 4) & 1) ? half : 0)) : n;
    t[ty + i][tx] = in[(size_t)(k0 + ty + i) * N + nsrc];
  }
  __syncthreads();
#pragma unroll
  for (int i = 0; i < 32; i += 8)
    out[(size_t)(n0 + ty + i) * K + k0 + tx] = f2b(t[tx][ty + i]);
}

// ---------------- MFMA GEMM: C[M][ldc] = A[M][K](bf16) * BT[N][K](bf16)^T ----------------
// EPI 0: store bf16. EPI 1: f32 residual add in place. EPI 2: fused SwiGLU.
// EPI 3: bf16 residual add in place.
template <int EPI>
__global__ __launch_bounds__(256) void gemm_k(const unsigned short* __restrict__ A,
                                              const unsigned short* __restrict__ BT,
                                              void* __restrict__ Cv, int K, int ldc) {
  __shared__ short lsA[128 * 64];
  __shared__ short lsB[128 * 64];
  const int tid = threadIdx.x;
  const int lane = tid & 63;
  const int wv = tid >> 6;
  const int wr = wv >> 1, wc = wv & 1;
  const int m0 = blockIdx.x * 128, n0 = blockIdx.y * 128;
  const int lr = lane & 15, kg = lane >> 4;

  f32x4 acc[4][4];
#pragma unroll
  for (int m = 0; m < 4; ++m)
#pragma unroll
    for (int n = 0; n < 4; ++n) acc[m][n] = (f32x4){0.f, 0.f, 0.f, 0.f};

  const int ObBase = wv * 4096 + lane * 16;  // byte offset of this lane's chunk slot
  for (int kt = 0; kt < K; kt += 64) {
#pragma unroll
    for (int i = 0; i < 4; ++i) {
      int Ob = ObBase + i * 1024;
      int row = Ob >> 7;                       // 0..127
      int ss = ((Ob >> 4) & 7) ^ (row & 7);    // inverse-swizzled source slot
      const unsigned short* ga = A + (size_t)(m0 + row) * K + kt + ss * 8;
      const unsigned short* gb = BT + (size_t)(n0 + row) * K + kt + ss * 8;
      load_lds16(ga, (char*)lsA + (wv * 4 + i) * 1024);
      load_lds16(gb, (char*)lsB + (wv * 4 + i) * 1024);
    }
    __syncthreads();
#pragma unroll
    for (int kk = 0; kk < 2; ++kk) {
      bf16x8 af[4], bfv[4];
#pragma unroll
      for (int m = 0; m < 4; ++m) {
        int row = wr * 64 + m * 16 + lr;
        int off = row * 128 + (((kk * 4 + kg) ^ (row & 7)) << 4);
        af[m] = *(const bf16x8*)((const char*)lsA + off);
      }
#pragma unroll
      for (int n = 0; n < 4; ++n) {
        int row = wc * 64 + n * 16 + lr;
        int off = row * 128 + (((kk * 4 + kg) ^ (row & 7)) << 4);
        bfv[n] = *(const bf16x8*)((const char*)lsB + off);
      }
#pragma unroll
      for (int m = 0; m < 4; ++m)
#pragma unroll
        for (int n = 0; n < 4; ++n)
          acc[m][n] = __builtin_amdgcn_mfma_f32_16x16x32_bf16(af[m], bfv[n], acc[m][n], 0, 0, 0);
    }
    __syncthreads();
  }

  if (EPI == 0) {
    unsigned short* Cb = (unsigned short*)Cv;
#pragma unroll
    for (int m = 0; m < 4; ++m)
#pragma unroll
      for (int n = 0; n < 4; ++n)
#pragma unroll
        for (int r = 0; r < 4; ++r) {
          int row = m0 + wr * 64 + m * 16 + kg * 4 + r;
          int col = n0 + wc * 64 + n * 16 + lr;
          Cb[(size_t)row * ldc + col] = f2b(acc[m][n][r]);
        }
  } else if (EPI == 1) {
    float* Cf = (float*)Cv;
#pragma unroll
    for (int m = 0; m < 4; ++m)
#pragma unroll
      for (int n = 0; n < 4; ++n)
#pragma unroll
        for (int r = 0; r < 4; ++r) {
          size_t idx = (size_t)(m0 + wr * 64 + m * 16 + kg * 4 + r) * ldc +
                       (n0 + wc * 64 + n * 16 + lr);
          Cf[idx] += acc[m][n][r];
        }
  } else if (EPI == 3) {
    unsigned short* Cb = (unsigned short*)Cv;
#pragma unroll
    for (int m = 0; m < 4; ++m)
#pragma unroll
      for (int n = 0; n < 4; ++n)
#pragma unroll
        for (int r = 0; r < 4; ++r) {
          size_t idx = (size_t)(m0 + wr * 64 + m * 16 + kg * 4 + r) * ldc +
                       (n0 + wc * 64 + n * 16 + lr);
          Cb[idx] = f2b(b2f(Cb[idx]) + acc[m][n][r]);
        }
  } else {
    unsigned short* Hb = (unsigned short*)Cv;
#pragma unroll
    for (int m = 0; m < 4; ++m)
#pragma unroll
      for (int p = 0; p < 2; ++p) {
        int n = p * 2;
        int colb = ((n0 + wc * 64 + n * 16) >> 1) + lr;
#pragma unroll
        for (int r = 0; r < 4; ++r) {
          float a = acc[m][n][r], bb = acc[m][n + 1][r];
          float hv = a / (1.f + __expf(-a)) * bb;  // silu(u1)*u2
          int row = m0 + wr * 64 + m * 16 + kg * 4 + r;
          Hb[(size_t)row * ldc + colb] = f2b(hv);
        }
      }
  }
}

// ---------------- fused block attention (one block = one (b,l,h)) ----------------
// RQ=0: all 144 query rows, Q from QKV, O[t][512] full layout.
// RQ=1: only 16 router queries (rows 128..143), Q from compact Qc[RT][512],
//       O written compact to RO[RT][512] (rt = bl*16 + r). K/V staging identical.
template <int RQ>
__global__ __launch_bounds__(256) void attn_k(const unsigned short* __restrict__ QKV,
                                              unsigned short* __restrict__ O,
                                              const float* __restrict__ cosT,
                                              const float* __restrict__ sinT,
                                              int blk0,
                                              const unsigned short* __restrict__ Qc) {
  __shared__ short Ks[144 * 72];     // rotated+scaled K, pad 72 for banks
  __shared__ short Vt[64 * 168];     // V transposed [dim][token], pad 168
  __shared__ short Ps[4][16 * 168];  // per-wave P tile
  int tid = threadIdx.x, lane = tid & 63, wv = tid >> 6;
  int lr = lane & 15, kg = lane >> 4;
  int blk = blockIdx.x, h = blk & 7, bl = blk >> 3;
  size_t t0 = (size_t)bl * 144;
  int posB = ((blk0 + bl) & 63) * 144;

  for (int idx = tid; idx < 144 * 4; idx += 256) {
    int j = idx >> 2, dg = idx & 3;
    const unsigned short* kr = QKV + (t0 + j) * 1536 + 512 + h * 64;
    u16x8 k1 = *(const u16x8*)(kr + dg * 8);
    u16x8 k2 = *(const u16x8*)(kr + 32 + dg * 8);
    const float* cp = cosT + (size_t)(posB + j) * 32 + dg * 8;
    const float* sp = sinT + (size_t)(posB + j) * 32 + dg * 8;
    u16x8 r1, r2;
#pragma unroll
    for (int e = 0; e < 8; ++e) {
      float c = cp[e], s = sp[e];
      float x1 = b2f(k1[e]) * 0.125f, x2 = b2f(k2[e]) * 0.125f;
      r1[e] = f2b(x1 * c + x2 * s);
      r2[e] = f2b(x2 * c - x1 * s);
    }
    *(u16x8*)(Ks + j * 72 + dg * 8) = r1;
    *(u16x8*)(Ks + j * 72 + 32 + dg * 8) = r2;
  }
  for (int idx = tid; idx < 144 * 8; idx += 256) {
    int j = idx >> 3, dg = idx & 7;
    u16x8 v = *(const u16x8*)(QKV + (t0 + j) * 1536 + 1024 + h * 64 + dg * 8);
#pragma unroll
    for (int e = 0; e < 8; ++e) Vt[(dg * 8 + e) * 168 + j] = v[e];
  }
  for (int idx = tid; idx < 64 * 16; idx += 256)
    Vt[(idx >> 4) * 168 + 144 + (idx & 15)] = 0;
  __syncthreads();

  if (!RQ || wv == 0)
  for (int rt = RQ ? 8 : wv; rt < 9; rt += 4) {
    int row = rt * 16 + lr;
    int pos = posB + row;
    const unsigned short* qr =
        RQ ? Qc + ((size_t)bl * 16 + lr) * 512 + h * 64
           : QKV + (t0 + row) * 1536 + h * 64;
    u16x8 q1 = *(const u16x8*)(qr + kg * 8);
    u16x8 q2 = *(const u16x8*)(qr + 32 + kg * 8);
    const float* cp = cosT + (size_t)pos * 32 + kg * 8;
    const float* sp = sinT + (size_t)pos * 32 + kg * 8;
    bf16x8 aq0, aq1;
#pragma unroll
    for (int e = 0; e < 8; ++e) {
      float c = cp[e], s = sp[e];
      float x1 = b2f(q1[e]), x2 = b2f(q2[e]);
      aq0[e] = (short)f2b(x1 * c + x2 * s);
      aq1[e] = (short)f2b(x2 * c - x1 * s);
    }
    f32x4 acc[9];
#pragma unroll
    for (int ct = 0; ct < 9; ++ct) acc[ct] = (f32x4){0.f, 0.f, 0.f, 0.f};
#pragma unroll
    for (int ct = 0; ct < 9; ++ct) {
      const short* kb = Ks + (ct * 16 + lr) * 72 + kg * 8;
      bf16x8 b0 = *(const bf16x8*)kb;
      bf16x8 b1 = *(const bf16x8*)(kb + 32);
      acc[ct] = __builtin_amdgcn_mfma_f32_16x16x32_bf16(aq0, b0, acc[ct], 0, 0, 0);
      acc[ct] = __builtin_amdgcn_mfma_f32_16x16x32_bf16(aq1, b1, acc[ct], 0, 0, 0);
    }
    float invs[4];
#pragma unroll
    for (int r = 0; r < 4; ++r) {
      float m = acc[0][r];
#pragma unroll
      for (int ct = 1; ct < 9; ++ct) m = fmaxf(m, acc[ct][r]);
#pragma unroll
      for (int off = 1; off < 16; off <<= 1) m = fmaxf(m, __shfl_xor(m, off));
      float sum = 0.f;
#pragma unroll
      for (int ct = 0; ct < 9; ++ct) {
        float e = __expf(acc[ct][r] - m);
        acc[ct][r] = e;
        sum += e;
      }
#pragma unroll
      for (int off = 1; off < 16; off <<= 1) sum += __shfl_xor(sum, off);
      invs[r] = 1.f / sum;
    }
    short* P = &Ps[wv][0];
#pragma unroll
    for (int ct = 0; ct < 9; ++ct)
#pragma unroll
      for (int r = 0; r < 4; ++r)
        P[(kg * 4 + r) * 168 + ct * 16 + lr] = (short)f2b(acc[ct][r] * invs[r]);
#pragma unroll
    for (int z = 0; z < 4; ++z) {
      int e = lane * 4 + z;
      P[(e >> 4) * 168 + 144 + (e & 15)] = 0;
    }
    f32x4 oacc[4];
#pragma unroll
    for (int n = 0; n < 4; ++n) oacc[n] = (f32x4){0.f, 0.f, 0.f, 0.f};
#pragma unroll
    for (int kc = 0; kc < 5; ++kc) {
      bf16x8 pa = *(const bf16x8*)(P + lr * 168 + kc * 32 + kg * 8);
#pragma unroll
      for (int n = 0; n < 4; ++n) {
        bf16x8 vb = *(const bf16x8*)(Vt + (n * 16 + lr) * 168 + kc * 32 + kg * 8);
        oacc[n] = __builtin_amdgcn_mfma_f32_16x16x32_bf16(pa, vb, oacc[n], 0, 0, 0);
      }
    }
#pragma unroll
    for (int n = 0; n < 4; ++n)
#pragma unroll
      for (int r = 0; r < 4; ++r) {
        if (RQ) {
          O[((size_t)bl * 16 + kg * 4 + r) * 512 + h * 64 + n * 16 + lr] = f2b(oacc[n][r]);
        } else {
          int orow = rt * 16 + kg * 4 + r;
          O[(t0 + orow) * 512 + h * 64 + n * 16 + lr] = f2b(oacc[n][r]);
        }
      }
  }
}

// ---------------- launcher ----------------
extern "C" void kernel_launch(void* const* d_in, const int* in_sizes, int n_in,
                              void* d_out, int out_size, void* d_ws, size_t ws_size,
                              hipStream_t stream) {
  (void)in_sizes; (void)n_in; (void)out_size;
  const float* x = (const float*)d_in[0];
  const float* rtok = (const float*)d_in[1];
  const float* aw[2] = {(const float*)d_in[2], (const float*)d_in[8]};
  const float* ow[2] = {(const float*)d_in[3], (const float*)d_in[9]};
  const float* uw[2] = {(const float*)d_in[4], (const float*)d_in[10]};
  const float* dw[2] = {(const float*)d_in[5], (const float*)d_in[11]};
  const float* an[2] = {(const float*)d_in[6], (const float*)d_in[12]};
  const float* fn[2] = {(const float*)d_in[7], (const float*)d_in[13]};

  // weights (16,777,216 B) + rope tables (2,359,296 B) are always resident.
  const size_t wfix = 16777216ull + 2359296ull;
  // tiers: {X dtype, chunks}. need = wfix + Xbytes + CT*5120 (XN + S1, bf16).
  const int tier_xb[5] = {0, 0, 0, 1, 1};
  const int tier_ch[5] = {2, 4, 8, 8, 16};
  int ti = -1;
  for (int i = 0; i < 5; ++i) {
    size_t xbytes = (size_t)T_TOK * (tier_xb[i] ? 1024 : 2048);
    size_t need = wfix + xbytes + ((size_t)T_TOK / tier_ch[i]) * 5120;
    if (ws_size >= need) { ti = i; break; }
  }
  if (ti < 0) {
    ws_marker_k<<<8192, 256, 0, stream>>>((float*)d_out, (float)(ws_size >> 20));
    return;
  }
  const int xbf = tier_xb[ti];
  const int chunks = tier_ch[ti];
  const int CT = T_TOK / chunks;   // multiple of 1152 -> divisible by 128 and 144
  const int MT = CT / 128, AB = CT / 144;
  const int RT = AB * 16;          // router rows per chunk (divisible by 128)

  char* ws = (char*)d_ws;
  size_t woff = 0;
  unsigned short *WqkvT[2], *WoT[2], *WupT[2], *WdnT[2];
  for (int l = 0; l < 2; ++l) {
    WqkvT[l] = (unsigned short*)(ws + woff); woff += 1536ull * 512 * 2;
    WoT[l]   = (unsigned short*)(ws + woff); woff += 512ull * 512 * 2;
    WupT[l]  = (unsigned short*)(ws + woff); woff += 4096ull * 512 * 2;
    WdnT[l]  = (unsigned short*)(ws + woff); woff += 512ull * 2048 * 2;
  }
  float* cosT = (float*)(ws + woff); woff += 9216ull * 32 * 4;
  float* sinT = (float*)(ws + woff); woff += 9216ull * 32 * 4;
  char* Xraw = ws + woff; woff += (size_t)T_TOK * (xbf ? 1024 : 2048);
  unsigned short* XN = (unsigned short*)(ws + woff);               // CT*512 bf16 (also O)
  unsigned short* S1 = (unsigned short*)(ws + woff + (size_t)CT * 1024);  // QKV / H
  // compact router buffers live in S1's tail (beyond the QKV region of CT*1536 shorts):
  unsigned short* RXN = S1 + (size_t)CT * 1536;        // RT*512 bf16
  unsigned short* RQ  = RXN + (size_t)RT * 512;        // RT*512 bf16
  unsigned short* RO  = RQ + (size_t)RT * 512;         // RT*512 bf16

  rope_table_k<<<1152, 256, 0, stream>>>(cosT, sinT);
  if (xbf)
    build_xm_bf16_k<<<9216, 256, 0, stream>>>(x, rtok, (unsigned short*)Xraw);
  else
    build_xm_f32_k<<<18432, 256, 0, stream>>>(x, rtok, (float*)Xraw);
  for (int l = 0; l < 2; ++l) {
    wconv_k<<<dim3(48, 16), 256, 0, stream>>>(aw[l], WqkvT[l], 512, 1536, 0);
    wconv_k<<<dim3(16, 16), 256, 0, stream>>>(ow[l], WoT[l], 512, 512, 0);
    wconv_k<<<dim3(128, 16), 256, 0, stream>>>(uw[l], WupT[l], 512, 4096, 1);
    wconv_k<<<dim3(16, 64), 256, 0, stream>>>(dw[l], WdnT[l], 2048, 512, 0);
  }

  // ---------------- layer 1: full (all rows feed layer-2 K/V) ----------------
  for (int c = 0; c < chunks; ++c) {
    char* Xc = Xraw + (size_t)c * CT * (xbf ? 1024 : 2048);
    if (xbf) {
      rmsnorm_k<1><<<CT / 4, 256, 0, stream>>>(Xc, an[0], XN);
      gemm_k<0><<<dim3(MT, 12), 256, 0, stream>>>(XN, WqkvT[0], (void*)S1, 512, 1536);
      attn_k<0><<<AB * 8, 256, 0, stream>>>(S1, XN, cosT, sinT, c * AB, nullptr);
      gemm_k<3><<<dim3(MT, 4), 256, 0, stream>>>(XN, WoT[0], (void*)Xc, 512, 512);
      rmsnorm_k<1><<<CT / 4, 256, 0, stream>>>(Xc, fn[0], XN);
      gemm_k<2><<<dim3(MT, 32), 256, 0, stream>>>(XN, WupT[0], (void*)S1, 512, 2048);
      gemm_k<3><<<dim3(MT, 4), 256, 0, stream>>>(S1, WdnT[0], (void*)Xc, 2048, 512);
    } else {
      rmsnorm_k<0><<<CT / 4, 256, 0, stream>>>(Xc, an[0], XN);
      gemm_k<0><<<dim3(MT, 12), 256, 0, stream>>>(XN, WqkvT[0], (void*)S1, 512, 1536);
      attn_k<0><<<AB * 8, 256, 0, stream>>>(S1, XN, cosT, sinT, c * AB, nullptr);
      gemm_k<1><<<dim3(MT, 4), 256, 0, stream>>>(XN, WoT[0], (void*)Xc, 512, 512);
      rmsnorm_k<0><<<CT / 4, 256, 0, stream>>>(Xc, fn[0], XN);
      gemm_k<2><<<dim3(MT, 32), 256, 0, stream>>>(XN, WupT[0], (void*)S1, 512, 2048);
      gemm_k<1><<<dim3(MT, 4), 256, 0, stream>>>(S1, WdnT[0], (void*)Xc, 2048, 512);
    }
  }

  // ---------------- layer 2: K/V full, everything else router rows only ----------------
  for (int c = 0; c < chunks; ++c) {
    char* Xc = Xraw + (size_t)c * CT * (xbf ? 1024 : 2048);
    float* outc = (float*)d_out + (size_t)c * RT * 512;
    // attn-norm on all rows (K/V need it)
    if (xbf) rmsnorm_k<1><<<CT / 4, 256, 0, stream>>>(Xc, an[1], XN);
    else     rmsnorm_k<0><<<CT / 4, 256, 0, stream>>>(Xc, an[1], XN);
    // compact router rows of XN
    gather_rxn_k<<<RT / 4, 256, 0, stream>>>(XN, RXN);
    // K,V for all rows (N-tiles 4..11 of qkv) -> S1 cols 512..1535
    gemm_k<0><<<dim3(MT, 8), 256, 0, stream>>>(XN, WqkvT[1] + 512 * 512,
                                               (void*)(S1 + 512), 512, 1536);
    // Q for router rows only (compact)
    gemm_k<0><<<dim3(RT / 128, 4), 256, 0, stream>>>(RXN, WqkvT[1], (void*)RQ, 512, 512);
    // attention: router queries only -> RO compact
    attn_k<1><<<AB * 8, 256, 0, stream>>>(S1, RO, cosT, sinT, c * AB, RQ);
    // residual base: X router rows -> d_out (f32)
    if (xbf) gather_rx_k<1><<<RT / 4, 256, 0, stream>>>(Xc, outc);
    else     gather_rx_k<0><<<RT / 4, 256, 0, stream>>>(Xc, outc);
    // o-proj + residual into d_out
    gemm_k<1><<<dim3(RT / 128, 4), 256, 0, stream>>>(RO, WoT[1], (void*)outc, 512, 512);
    // ffn-norm on router rows (f32 in d_out) -> RXN (reuse)
    rmsnorm_k<0><<<RT / 4, 256, 0, stream>>>(outc, fn[1], RXN);
    // up + SwiGLU -> H_r (S1 base, RT x 2048)
    gemm_k<2><<<dim3(RT / 128, 32), 256, 0, stream>>>(RXN, WupT[1], (void*)S1, 512, 2048);
    // down + residual into d_out  => final router outputs
    gemm_k<1><<<dim3(RT / 128, 4), 256, 0, stream>>>(S1, WdnT[1], (void*)outc, 2048, 512);
  }
}

// Round 7
// 970.822 us; speedup vs baseline: 1.5379x; 1.0976x over previous
//
#include <hip/hip_runtime.h>

// ---------------- types & helpers ----------------
typedef __attribute__((ext_vector_type(8))) short bf16x8;
typedef __attribute__((ext_vector_type(4))) float f32x4;
typedef __attribute__((ext_vector_type(8))) unsigned short u16x8;

static __device__ __forceinline__ float b2f(unsigned short u) {
  unsigned v = ((unsigned)u) << 16;
  float f;
  __builtin_memcpy(&f, &v, 4);
  return f;
}
static __device__ __forceinline__ unsigned short f2b(float f) {
  unsigned u;
  __builtin_memcpy(&u, &f, 4);
  u = u + 0x7FFFu + ((u >> 16) & 1u);
  return (unsigned short)(u >> 16);
}
static __device__ __forceinline__ void load_lds16(const void* g, void* l) {
  __builtin_amdgcn_global_load_lds((const __attribute__((address_space(1))) unsigned int*)g,
                                   (__attribute__((address_space(3))) unsigned int*)l,
                                   16, 0, 0);
}

#define T_TOK 36864  // 4 * 64 * 144

// ---------------- fallback marker (ws too small) ----------------
__global__ void ws_marker_k(float* __restrict__ out, float wsmb) {
  int i = blockIdx.x * 256 + threadIdx.x;
  out[i] = (i == 0) ? wsmb : 0.f;
}

// ---------------- rope table (f32, matches jax f32 trig) ----------------
__global__ void rope_table_k(float* __restrict__ cosT, float* __restrict__ sinT) {
  int idx = blockIdx.x * 256 + threadIdx.x;  // < 9216*32, [pos][i]
  int i = idx & 31, p = idx >> 5;
  float invf = __powf(10000.f, -(float)i / 32.f);
  float ang = (float)p * invf;
  float s, c;
  __sincosf(ang, &s, &c);
  cosT[idx] = c;
  sinT[idx] = s;
}

// ---------------- RMSNorm reading merged source (x / router_token) ----------------
// row r (chunk-local) -> global token tg0+r -> block bl, intra j; j<128 from x, else rt.
__global__ __launch_bounds__(256) void rmsnorm_src_k(const float* __restrict__ x,
                                                     const float* __restrict__ rt,
                                                     const float* __restrict__ w,
                                                     unsigned short* __restrict__ XN,
                                                     int tg0) {
  int lane = threadIdx.x & 63, wv = threadIdx.x >> 6;
  int row = blockIdx.x * 4 + wv;
  int tg = tg0 + row;
  int bl = tg / 144, j = tg - bl * 144;
  const float* src = (j < 128)
      ? x + ((size_t)((bl >> 6) * 8192 + (bl & 63) * 128 + j)) * 512
      : rt + (size_t)(j - 128) * 512;
  const float4* xr = (const float4*)src;
  float4 a = xr[lane * 2], b = xr[lane * 2 + 1];
  float v[8] = {a.x, a.y, a.z, a.w, b.x, b.y, b.z, b.w};
  float ss = 0.f;
#pragma unroll
  for (int e = 0; e < 8; ++e) ss += v[e] * v[e];
#pragma unroll
  for (int off = 32; off; off >>= 1) ss += __shfl_xor(ss, off);
  float inv = rsqrtf(ss * (1.0f / 512.0f) + 1e-5f);
  const float4* w4 = (const float4*)w;
  float4 w0 = w4[lane * 2], w1 = w4[lane * 2 + 1];
  float wf[8] = {w0.x, w0.y, w0.z, w0.w, w1.x, w1.y, w1.z, w1.w};
  u16x8 o;
#pragma unroll
  for (int e = 0; e < 8; ++e) o[e] = f2b(v[e] * inv * wf[e]);
  *(u16x8*)(XN + (size_t)row * 512 + lane * 8) = o;
}

// ---------------- RMSNorm X -> bf16 (one wave per row); XBF: X bf16 vs f32 ----------------
template <int XBF>
__global__ __launch_bounds__(256) void rmsnorm_k(const void* __restrict__ Xv,
                                                 const float* __restrict__ w,
                                                 unsigned short* __restrict__ XN) {
  int lane = threadIdx.x & 63, wv = threadIdx.x >> 6;
  size_t row = (size_t)blockIdx.x * 4 + wv;
  float v[8];
  if (XBF) {
    u16x8 a = *(const u16x8*)((const unsigned short*)Xv + row * 512 + lane * 8);
#pragma unroll
    for (int e = 0; e < 8; ++e) v[e] = b2f(a[e]);
  } else {
    const float4* xr = (const float4*)((const float*)Xv + row * 512);
    float4 a = xr[lane * 2], b = xr[lane * 2 + 1];
    v[0] = a.x; v[1] = a.y; v[2] = a.z; v[3] = a.w;
    v[4] = b.x; v[5] = b.y; v[6] = b.z; v[7] = b.w;
  }
  float ss = 0.f;
#pragma unroll
  for (int e = 0; e < 8; ++e) ss += v[e] * v[e];
#pragma unroll
  for (int off = 32; off; off >>= 1) ss += __shfl_xor(ss, off);
  float inv = rsqrtf(ss * (1.0f / 512.0f) + 1e-5f);
  const float4* w4 = (const float4*)w;
  float4 w0 = w4[lane * 2], w1 = w4[lane * 2 + 1];
  float wf[8] = {w0.x, w0.y, w0.z, w0.w, w1.x, w1.y, w1.z, w1.w};
  u16x8 o;
#pragma unroll
  for (int e = 0; e < 8; ++e) o[e] = f2b(v[e] * inv * wf[e]);
  *(u16x8*)(XN + row * 512 + lane * 8) = o;
}

// ---------------- gather router rows of XN (bf16) -> compact RXN ----------------
__global__ void gather_rxn_k(const unsigned short* __restrict__ XN,
                             unsigned short* __restrict__ RXN) {
  int i = blockIdx.x * 256 + threadIdx.x;  // u16x8 chunks, < RT*64
  int c8 = i & 63, rt = i >> 6;
  int t = (rt >> 4) * 144 + 128 + (rt & 15);
  *(u16x8*)(RXN + (size_t)rt * 512 + c8 * 8) =
      *(const u16x8*)(XN + (size_t)t * 512 + c8 * 8);
}

// ---------------- gather router rows of X (bf16) -> d_out chunk (f32) ----------------
__global__ void gather_rx_k(const unsigned short* __restrict__ X, float* __restrict__ outc) {
  int i = blockIdx.x * 256 + threadIdx.x;  // 8-elem chunks, < RT*64
  int c8 = i & 63, rt = i >> 6;
  int t = (rt >> 4) * 144 + 128 + (rt & 15);
  u16x8 v = *(const u16x8*)(X + (size_t)t * 512 + c8 * 8);
  float* dst = outc + (size_t)rt * 512 + c8 * 8;
  *(float4*)dst = (float4){b2f(v[0]), b2f(v[1]), b2f(v[2]), b2f(v[3])};
  *(float4*)(dst + 4) = (float4){b2f(v[4]), b2f(v[5]), b2f(v[6]), b2f(v[7])};
}

// ---------------- weight transpose-convert f32[K][N] -> bf16[N][K] ----------------
__global__ void wconv_k(const float* __restrict__ in, unsigned short* __restrict__ out,
                        int K, int N, int upmap) {
  __shared__ float t[32][33];
  int tx = threadIdx.x & 31, ty = threadIdx.x >> 5;  // ty 0..7
  int n0 = blockIdx.x * 32, k0 = blockIdx.y * 32;
  int half = N >> 1;
#pragma unroll
  for (int i = 0; i < 32; i += 8) {
    int n = n0 + tx;
    int nsrc = upmap ? (((n >> 5) << 4) + (n & 15) + (((n >> 4) & 1) ? half : 0)) : n;
    t[ty + i][tx] = in[(size_t)(k0 + ty + i) * N + nsrc];
  }
  __syncthreads();
#pragma unroll
  for (int i = 0; i < 32; i += 8)
    out[(size_t)(n0 + ty + i) * K + k0 + tx] = f2b(t[tx][ty + i]);
}

// ---------------- MFMA GEMM: C[M][ldc] = A[M][K](bf16) * BT[N][K](bf16)^T ----------------
// EPI 0: store bf16. EPI 1: f32 residual add in place. EPI 2: fused SwiGLU.
// EPI 3: bf16 residual add in place. EPI 5: bf16 store of acc + merged-source residual
// (residual fetched from x / router_token via token mapping; ldc must be 512).
template <int EPI>
__global__ __launch_bounds__(256) void gemm_k(const unsigned short* __restrict__ A,
                                              const unsigned short* __restrict__ BT,
                                              void* __restrict__ Cv, int K, int ldc,
                                              int tg0, const float* __restrict__ xsrc,
                                              const float* __restrict__ rtsrc) {
  __shared__ short lsA[128 * 64];
  __shared__ short lsB[128 * 64];
  const int tid = threadIdx.x;
  const int lane = tid & 63;
  const int wv = tid >> 6;
  const int wr = wv >> 1, wc = wv & 1;
  // XCD-aware swizzle of the M dimension (contiguous M-chunk per XCD) for L2 A-panel reuse.
  int bx = blockIdx.x;
  if ((gridDim.x & 7) == 0) {
    int cpx = gridDim.x >> 3;
    bx = (bx & 7) * cpx + (bx >> 3);
  }
  const int m0 = bx * 128, n0 = blockIdx.y * 128;
  const int lr = lane & 15, kg = lane >> 4;

  f32x4 acc[4][4];
#pragma unroll
  for (int m = 0; m < 4; ++m)
#pragma unroll
    for (int n = 0; n < 4; ++n) acc[m][n] = (f32x4){0.f, 0.f, 0.f, 0.f};

  const int ObBase = wv * 4096 + lane * 16;  // byte offset of this lane's chunk slot
  for (int kt = 0; kt < K; kt += 64) {
#pragma unroll
    for (int i = 0; i < 4; ++i) {
      int Ob = ObBase + i * 1024;
      int row = Ob >> 7;                       // 0..127
      int ss = ((Ob >> 4) & 7) ^ (row & 7);    // inverse-swizzled source slot
      const unsigned short* ga = A + (size_t)(m0 + row) * K + kt + ss * 8;
      const unsigned short* gb = BT + (size_t)(n0 + row) * K + kt + ss * 8;
      load_lds16(ga, (char*)lsA + (wv * 4 + i) * 1024);
      load_lds16(gb, (char*)lsB + (wv * 4 + i) * 1024);
    }
    __syncthreads();
#pragma unroll
    for (int kk = 0; kk < 2; ++kk) {
      bf16x8 af[4], bfv[4];
#pragma unroll
      for (int m = 0; m < 4; ++m) {
        int row = wr * 64 + m * 16 + lr;
        int off = row * 128 + (((kk * 4 + kg) ^ (row & 7)) << 4);
        af[m] = *(const bf16x8*)((const char*)lsA + off);
      }
#pragma unroll
      for (int n = 0; n < 4; ++n) {
        int row = wc * 64 + n * 16 + lr;
        int off = row * 128 + (((kk * 4 + kg) ^ (row & 7)) << 4);
        bfv[n] = *(const bf16x8*)((const char*)lsB + off);
      }
#pragma unroll
      for (int m = 0; m < 4; ++m)
#pragma unroll
        for (int n = 0; n < 4; ++n)
          acc[m][n] = __builtin_amdgcn_mfma_f32_16x16x32_bf16(af[m], bfv[n], acc[m][n], 0, 0, 0);
    }
    __syncthreads();
  }

  if (EPI == 0) {
    unsigned short* Cb = (unsigned short*)Cv;
#pragma unroll
    for (int m = 0; m < 4; ++m)
#pragma unroll
      for (int n = 0; n < 4; ++n)
#pragma unroll
        for (int r = 0; r < 4; ++r) {
          int row = m0 + wr * 64 + m * 16 + kg * 4 + r;
          int col = n0 + wc * 64 + n * 16 + lr;
          Cb[(size_t)row * ldc + col] = f2b(acc[m][n][r]);
        }
  } else if (EPI == 1) {
    float* Cf = (float*)Cv;
#pragma unroll
    for (int m = 0; m < 4; ++m)
#pragma unroll
      for (int n = 0; n < 4; ++n)
#pragma unroll
        for (int r = 0; r < 4; ++r) {
          size_t idx = (size_t)(m0 + wr * 64 + m * 16 + kg * 4 + r) * ldc +
                       (n0 + wc * 64 + n * 16 + lr);
          Cf[idx] += acc[m][n][r];
        }
  } else if (EPI == 3) {
    unsigned short* Cb = (unsigned short*)Cv;
#pragma unroll
    for (int m = 0; m < 4; ++m)
#pragma unroll
      for (int n = 0; n < 4; ++n)
#pragma unroll
        for (int r = 0; r < 4; ++r) {
          size_t idx = (size_t)(m0 + wr * 64 + m * 16 + kg * 4 + r) * ldc +
                       (n0 + wc * 64 + n * 16 + lr);
          Cb[idx] = f2b(b2f(Cb[idx]) + acc[m][n][r]);
        }
  } else if (EPI == 5) {
    unsigned short* Cb = (unsigned short*)Cv;
#pragma unroll
    for (int m = 0; m < 4; ++m)
#pragma unroll
      for (int n = 0; n < 4; ++n)
#pragma unroll
        for (int r = 0; r < 4; ++r) {
          int row = m0 + wr * 64 + m * 16 + kg * 4 + r;
          int col = n0 + wc * 64 + n * 16 + lr;
          int tg = tg0 + row;
          int bl = tg / 144, j = tg - bl * 144;
          float src = (j < 128)
              ? xsrc[((size_t)((bl >> 6) * 8192 + (bl & 63) * 128 + j)) * 512 + col]
              : rtsrc[(size_t)(j - 128) * 512 + col];
          Cb[(size_t)row * ldc + col] = f2b(src + acc[m][n][r]);
        }
  } else {
    unsigned short* Hb = (unsigned short*)Cv;
#pragma unroll
    for (int m = 0; m < 4; ++m)
#pragma unroll
      for (int p = 0; p < 2; ++p) {
        int n = p * 2;
        int colb = ((n0 + wc * 64 + n * 16) >> 1) + lr;
#pragma unroll
        for (int r = 0; r < 4; ++r) {
          float a = acc[m][n][r], bb = acc[m][n + 1][r];
          float hv = a / (1.f + __expf(-a)) * bb;  // silu(u1)*u2
          int row = m0 + wr * 64 + m * 16 + kg * 4 + r;
          Hb[(size_t)row * ldc + colb] = f2b(hv);
        }
      }
  }
}

// ---------------- fused block attention (one block = one (b,l,h)) ----------------
// RQ=0: all 144 query rows, Q from QKV, O[t][512] full layout.
// RQ=1: only 16 router queries (rows 128..143), Q from compact Qc[RT][512],
//       O written compact to RO[RT][512] (rt = bl*16 + r). K/V staging identical.
template <int RQ>
__global__ __launch_bounds__(256) void attn_k(const unsigned short* __restrict__ QKV,
                                              unsigned short* __restrict__ O,
                                              const float* __restrict__ cosT,
                                              const float* __restrict__ sinT,
                                              int blk0,
                                              const unsigned short* __restrict__ Qc) {
  __shared__ short Ks[144 * 72];     // rotated+scaled K, pad 72 for banks
  __shared__ short Vt[64 * 168];     // V transposed [dim][token], pad 168
  __shared__ short Ps[4][16 * 168];  // per-wave P tile
  int tid = threadIdx.x, lane = tid & 63, wv = tid >> 6;
  int lr = lane & 15, kg = lane >> 4;
  int blk = blockIdx.x, h = blk & 7, bl = blk >> 3;
  size_t t0 = (size_t)bl * 144;
  int posB = ((blk0 + bl) & 63) * 144;

  for (int idx = tid; idx < 144 * 4; idx += 256) {
    int j = idx >> 2, dg = idx & 3;
    const unsigned short* kr = QKV + (t0 + j) * 1536 + 512 + h * 64;
    u16x8 k1 = *(const u16x8*)(kr + dg * 8);
    u16x8 k2 = *(const u16x8*)(kr + 32 + dg * 8);
    const float* cp = cosT + (size_t)(posB + j) * 32 + dg * 8;
    const float* sp = sinT + (size_t)(posB + j) * 32 + dg * 8;
    u16x8 r1, r2;
#pragma unroll
    for (int e = 0; e < 8; ++e) {
      float c = cp[e], s = sp[e];
      float x1 = b2f(k1[e]) * 0.125f, x2 = b2f(k2[e]) * 0.125f;
      r1[e] = f2b(x1 * c + x2 * s);
      r2[e] = f2b(x2 * c - x1 * s);
    }
    *(u16x8*)(Ks + j * 72 + dg * 8) = r1;
    *(u16x8*)(Ks + j * 72 + 32 + dg * 8) = r2;
  }
  for (int idx = tid; idx < 144 * 8; idx += 256) {
    int j = idx >> 3, dg = idx & 7;
    u16x8 v = *(const u16x8*)(QKV + (t0 + j) * 1536 + 1024 + h * 64 + dg * 8);
#pragma unroll
    for (int e = 0; e < 8; ++e) Vt[(dg * 8 + e) * 168 + j] = v[e];
  }
  for (int idx = tid; idx < 64 * 16; idx += 256)
    Vt[(idx >> 4) * 168 + 144 + (idx & 15)] = 0;
  __syncthreads();

  if (!RQ || wv == 0)
  for (int rt = RQ ? 8 : wv; rt < 9; rt += 4) {
    int row = rt * 16 + lr;
    int pos = posB + row;
    const unsigned short* qr =
        RQ ? Qc + ((size_t)bl * 16 + lr) * 512 + h * 64
           : QKV + (t0 + row) * 1536 + h * 64;
    u16x8 q1 = *(const u16x8*)(qr + kg * 8);
    u16x8 q2 = *(const u16x8*)(qr + 32 + kg * 8);
    const float* cp = cosT + (size_t)pos * 32 + kg * 8;
    const float* sp = sinT + (size_t)pos * 32 + kg * 8;
    bf16x8 aq0, aq1;
#pragma unroll
    for (int e = 0; e < 8; ++e) {
      float c = cp[e], s = sp[e];
      float x1 = b2f(q1[e]), x2 = b2f(q2[e]);
      aq0[e] = (short)f2b(x1 * c + x2 * s);
      aq1[e] = (short)f2b(x2 * c - x1 * s);
    }
    f32x4 acc[9];
#pragma unroll
    for (int ct = 0; ct < 9; ++ct) acc[ct] = (f32x4){0.f, 0.f, 0.f, 0.f};
#pragma unroll
    for (int ct = 0; ct < 9; ++ct) {
      const short* kb = Ks + (ct * 16 + lr) * 72 + kg * 8;
      bf16x8 b0 = *(const bf16x8*)kb;
      bf16x8 b1 = *(const bf16x8*)(kb + 32);
      acc[ct] = __builtin_amdgcn_mfma_f32_16x16x32_bf16(aq0, b0, acc[ct], 0, 0, 0);
      acc[ct] = __builtin_amdgcn_mfma_f32_16x16x32_bf16(aq1, b1, acc[ct], 0, 0, 0);
    }
    float invs[4];
#pragma unroll
    for (int r = 0; r < 4; ++r) {
      float m = acc[0][r];
#pragma unroll
      for (int ct = 1; ct < 9; ++ct) m = fmaxf(m, acc[ct][r]);
#pragma unroll
      for (int off = 1; off < 16; off <<= 1) m = fmaxf(m, __shfl_xor(m, off));
      float sum = 0.f;
#pragma unroll
      for (int ct = 0; ct < 9; ++ct) {
        float e = __expf(acc[ct][r] - m);
        acc[ct][r] = e;
        sum += e;
      }
#pragma unroll
      for (int off = 1; off < 16; off <<= 1) sum += __shfl_xor(sum, off);
      invs[r] = 1.f / sum;
    }
    short* P = &Ps[wv][0];
#pragma unroll
    for (int ct = 0; ct < 9; ++ct)
#pragma unroll
      for (int r = 0; r < 4; ++r)
        P[(kg * 4 + r) * 168 + ct * 16 + lr] = (short)f2b(acc[ct][r] * invs[r]);
#pragma unroll
    for (int z = 0; z < 4; ++z) {
      int e = lane * 4 + z;
      P[(e >> 4) * 168 + 144 + (e & 15)] = 0;
    }
    f32x4 oacc[4];
#pragma unroll
    for (int n = 0; n < 4; ++n) oacc[n] = (f32x4){0.f, 0.f, 0.f, 0.f};
#pragma unroll
    for (int kc = 0; kc < 5; ++kc) {
      bf16x8 pa = *(const bf16x8*)(P + lr * 168 + kc * 32 + kg * 8);
#pragma unroll
      for (int n = 0; n < 4; ++n) {
        bf16x8 vb = *(const bf16x8*)(Vt + (n * 16 + lr) * 168 + kc * 32 + kg * 8);
        oacc[n] = __builtin_amdgcn_mfma_f32_16x16x32_bf16(pa, vb, oacc[n], 0, 0, 0);
      }
    }
#pragma unroll
    for (int n = 0; n < 4; ++n)
#pragma unroll
      for (int r = 0; r < 4; ++r) {
        if (RQ) {
          O[((size_t)bl * 16 + kg * 4 + r) * 512 + h * 64 + n * 16 + lr] = f2b(oacc[n][r]);
        } else {
          int orow = rt * 16 + kg * 4 + r;
          O[(t0 + orow) * 512 + h * 64 + n * 16 + lr] = f2b(oacc[n][r]);
        }
      }
  }
}

// ---------------- launcher ----------------
extern "C" void kernel_launch(void* const* d_in, const int* in_sizes, int n_in,
                              void* d_out, int out_size, void* d_ws, size_t ws_size,
                              hipStream_t stream) {
  (void)in_sizes; (void)n_in; (void)out_size;
  const float* x = (const float*)d_in[0];
  const float* rtok = (const float*)d_in[1];
  const float* aw[2] = {(const float*)d_in[2], (const float*)d_in[8]};
  const float* ow[2] = {(const float*)d_in[3], (const float*)d_in[9]};
  const float* uw[2] = {(const float*)d_in[4], (const float*)d_in[10]};
  const float* dw[2] = {(const float*)d_in[5], (const float*)d_in[11]};
  const float* an[2] = {(const float*)d_in[6], (const float*)d_in[12]};
  const float* fn[2] = {(const float*)d_in[7], (const float*)d_in[13]};

  // weights (16,777,216 B) + rope tables (2,359,296 B) + X bf16 (37,748,736 B) resident.
  const size_t wfix = 16777216ull + 2359296ull + (size_t)T_TOK * 1024;
  // tiers: chunks. need = wfix + CT*5120 (XN + S1, bf16).
  const int tier_ch[4] = {1, 2, 4, 8};
  int ti = -1;
  for (int i = 0; i < 4; ++i) {
    size_t need = wfix + ((size_t)T_TOK / tier_ch[i]) * 5120;
    if (ws_size >= need) { ti = i; break; }
  }
  if (ti < 0) {
    ws_marker_k<<<8192, 256, 0, stream>>>((float*)d_out, (float)(ws_size >> 20));
    return;
  }
  const int chunks = tier_ch[ti];
  const int CT = T_TOK / chunks;   // multiple of 1152 -> divisible by 128 and 144
  const int MT = CT / 128, AB = CT / 144;
  const int RT = AB * 16;          // router rows per chunk (divisible by 128)

  char* ws = (char*)d_ws;
  size_t woff = 0;
  unsigned short *WqkvT[2], *WoT[2], *WupT[2], *WdnT[2];
  for (int l = 0; l < 2; ++l) {
    WqkvT[l] = (unsigned short*)(ws + woff); woff += 1536ull * 512 * 2;
    WoT[l]   = (unsigned short*)(ws + woff); woff += 512ull * 512 * 2;
    WupT[l]  = (unsigned short*)(ws + woff); woff += 4096ull * 512 * 2;
    WdnT[l]  = (unsigned short*)(ws + woff); woff += 512ull * 2048 * 2;
  }
  float* cosT = (float*)(ws + woff); woff += 9216ull * 32 * 4;
  float* sinT = (float*)(ws + woff); woff += 9216ull * 32 * 4;
  unsigned short* X = (unsigned short*)(ws + woff); woff += (size_t)T_TOK * 1024;
  unsigned short* XN = (unsigned short*)(ws + woff);                     // CT*512 bf16 (also O)
  unsigned short* S1 = (unsigned short*)(ws + woff + (size_t)CT * 1024); // QKV / H
  // compact router buffers in S1's tail (beyond QKV region of CT*1536 shorts):
  unsigned short* RXN = S1 + (size_t)CT * 1536;        // RT*512 bf16
  unsigned short* RQb = RXN + (size_t)RT * 512;        // RT*512 bf16
  unsigned short* RO  = RQb + (size_t)RT * 512;        // RT*512 bf16

  rope_table_k<<<1152, 256, 0, stream>>>(cosT, sinT);
  for (int l = 0; l < 2; ++l) {
    wconv_k<<<dim3(48, 16), 256, 0, stream>>>(aw[l], WqkvT[l], 512, 1536, 0);
    wconv_k<<<dim3(16, 16), 256, 0, stream>>>(ow[l], WoT[l], 512, 512, 0);
    wconv_k<<<dim3(128, 16), 256, 0, stream>>>(uw[l], WupT[l], 512, 4096, 1);
    wconv_k<<<dim3(16, 64), 256, 0, stream>>>(dw[l], WdnT[l], 2048, 512, 0);
  }

  // ---------------- layer 1: full rows; X materialized (bf16) at o-proj ----------------
  for (int c = 0; c < chunks; ++c) {
    unsigned short* Xc = X + (size_t)c * CT * 512;
    int tg0 = c * CT;
    rmsnorm_src_k<<<CT / 4, 256, 0, stream>>>(x, rtok, an[0], XN, tg0);
    gemm_k<0><<<dim3(MT, 12), 256, 0, stream>>>(XN, WqkvT[0], (void*)S1, 512, 1536, 0, nullptr, nullptr);
    attn_k<0><<<AB * 8, 256, 0, stream>>>(S1, XN, cosT, sinT, c * AB, nullptr);
    gemm_k<5><<<dim3(MT, 4), 256, 0, stream>>>(XN, WoT[0], (void*)Xc, 512, 512, tg0, x, rtok);
    rmsnorm_k<1><<<CT / 4, 256, 0, stream>>>(Xc, fn[0], XN);
    gemm_k<2><<<dim3(MT, 32), 256, 0, stream>>>(XN, WupT[0], (void*)S1, 512, 2048, 0, nullptr, nullptr);
    gemm_k<3><<<dim3(MT, 4), 256, 0, stream>>>(S1, WdnT[0], (void*)Xc, 2048, 512, 0, nullptr, nullptr);
  }

  // ---------------- layer 2: K/V full, everything else router rows only ----------------
  for (int c = 0; c < chunks; ++c) {
    unsigned short* Xc = X + (size_t)c * CT * 512;
    float* outc = (float*)d_out + (size_t)c * RT * 512;
    rmsnorm_k<1><<<CT / 4, 256, 0, stream>>>(Xc, an[1], XN);
    gather_rxn_k<<<RT / 4, 256, 0, stream>>>(XN, RXN);
    gemm_k<0><<<dim3(MT, 8), 256, 0, stream>>>(XN, WqkvT[1] + 512 * 512,
                                               (void*)(S1 + 512), 512, 1536, 0, nullptr, nullptr);
    gemm_k<0><<<dim3(RT / 128, 4), 256, 0, stream>>>(RXN, WqkvT[1], (void*)RQb, 512, 512, 0, nullptr, nullptr);
    attn_k<1><<<AB * 8, 256, 0, stream>>>(S1, RO, cosT, sinT, c * AB, RQb);
    gather_rx_k<<<RT / 4, 256, 0, stream>>>(Xc, outc);
    gemm_k<1><<<dim3(RT / 128, 4), 256, 0, stream>>>(RO, WoT[1], (void*)outc, 512, 512, 0, nullptr, nullptr);
    rmsnorm_k<0><<<RT / 4, 256, 0, stream>>>(outc, fn[1], RXN);
    gemm_k<2><<<dim3(RT / 128, 32), 256, 0, stream>>>(RXN, WupT[1], (void*)S1, 512, 2048, 0, nullptr, nullptr);
    gemm_k<1><<<dim3(RT / 128, 4), 256, 0, stream>>>(S1, WdnT[1], (void*)outc, 2048, 512, 0, nullptr, nullptr);
  }
}